// Round 6
// baseline (1457.806 us; speedup 1.0000x reference)
//
#include <hip/hip_runtime.h>
#include <hip/hip_bf16.h>

#define NN 100000
#define NE 1600000
#define NBK 782           // dst buckets of 128 nodes
#define BCAP 2688         // padded bucket capacity (mean ~2046, sd ~45 -> +14 sigma)
#define BIN_CHUNK 16384
#define BIN_BLKS 98       // 98*16384 >= NE

typedef __attribute__((ext_vector_type(8))) short bf16x8;
typedef __attribute__((ext_vector_type(4))) float f32x4;

__device__ inline unsigned short f2bf(float f) {
    union { __hip_bfloat16 h; unsigned short u; } c;
    c.h = __float2bfloat16(f);
    return c.u;
}

// ---- bucket cursors init ---------------------------------------------------
__global__ void k_init(int* __restrict__ gcur) {
    int i = blockIdx.x * 256 + threadIdx.x;
    if (i < NBK) gcur[i] = i * BCAP;
}

// ---- weights -> bf16, Wcat[fo][0:64]=Wl[fo][:], [64:128]=Wr[fo][:] ---------
__global__ void k_wcvt(const float* __restrict__ Wl1, const float* __restrict__ Wr1,
                       const float* __restrict__ Wl2, const float* __restrict__ Wr2,
                       unsigned short* __restrict__ Wc1, unsigned short* __restrict__ Wc2) {
    int e = blockIdx.x * 256 + threadIdx.x;
    if (e < 4096) {
        int fo = e >> 6, k = e & 63;
        Wc1[fo * 128 + k]      = f2bf(Wl1[e]);
        Wc1[fo * 128 + 64 + k] = f2bf(Wr1[e]);
        Wc2[fo * 128 + k]      = f2bf(Wl2[e]);
        Wc2[fo * 128 + 64 + k] = f2bf(Wr2[e]);
    }
}

// ---- x (f32) -> bf16 table --------------------------------------------------
__global__ __launch_bounds__(256) void k_xcvt(const float* __restrict__ x,
                                              unsigned short* __restrict__ xb) {
    int i = blockIdx.x * 256 + threadIdx.x;     // 8 elements per thread
    if (i >= NN * 64 / 8) return;
    const float4* p = (const float4*)(x + (size_t)i * 8);
    float4 v0 = p[0], v1 = p[1];
    union { bf16x8 v; unsigned short u[8]; } c;
    c.u[0] = f2bf(v0.x); c.u[1] = f2bf(v0.y); c.u[2] = f2bf(v0.z); c.u[3] = f2bf(v0.w);
    c.u[4] = f2bf(v1.x); c.u[5] = f2bf(v1.y); c.u[6] = f2bf(v1.z); c.u[7] = f2bf(v1.w);
    *(bf16x8*)(xb + (size_t)i * 8) = c.v;
}

// ---- bin edges by dst>>7 into padded bucket regions ------------------------
// packed word = (dst&127)<<17 | src   (src < 2^17)
__global__ __launch_bounds__(256) void k_bin(const int* __restrict__ src,
                                             const int* __restrict__ dst,
                                             int* __restrict__ gcur,
                                             unsigned* __restrict__ binned) {
    __shared__ int hist[NBK];
    __shared__ int base[NBK];
    __shared__ int lcur[NBK];
    const int t = threadIdx.x;
    const int e0 = blockIdx.x * BIN_CHUNK;
    const int n = min(BIN_CHUNK, NE - e0);
    for (int i = t; i < NBK; i += 256) { hist[i] = 0; lcur[i] = 0; }
    __syncthreads();
    for (int i = t; i < n; i += 256)
        atomicAdd(&hist[dst[e0 + i] >> 7], 1);
    __syncthreads();
    for (int i = t; i < NBK; i += 256) {
        int h = hist[i];
        base[i] = h ? atomicAdd(&gcur[i], h) : 0;
    }
    __syncthreads();
    for (int i = t; i < n; i += 256) {
        int d = dst[e0 + i];
        int s = src[e0 + i];
        int b = d >> 7;
        int p = base[b] + atomicAdd(&lcur[b], 1);
        binned[p] = ((unsigned)(d & 127) << 17) | (unsigned)s;
    }
}

// ---- Edge-centric aggregation: one block per 128-node bucket ----------------
// 64 groups of 8 lanes; group streams unsorted bucket edges, gathers the
// 128 B bf16 row, LDS-atomicAdd f32 into acc[dl][.]; deg counted in LDS.
// Epilogue scales by 1/max(deg,1) and writes A as bf16 [NN][64].
__global__ __launch_bounds__(512) void k_agg(const unsigned short* __restrict__ feat,
                                             const unsigned* __restrict__ binned,
                                             const int* __restrict__ gcur,
                                             unsigned short* __restrict__ A) {
    __shared__ float acc[128 * 68];     // 34.8 KB, +4 f32 row pad
    __shared__ int ldeg[128];
    const int b = blockIdx.x;
    const int t = threadIdx.x;
    const int base = b * BCAP;
    const int cnt = min(gcur[b] - base, BCAP);

    for (int i = t; i < 128 * 68; i += 512) acc[i] = 0.f;
    if (t < 128) ldeg[t] = 0;
    __syncthreads();

    const int g = t >> 3;
    const int p = t & 7;

    #define ACC8(row, u)                                           \
        atomicAdd((row) + 0, __uint_as_float((u).x << 16));        \
        atomicAdd((row) + 1, __uint_as_float((u).x & 0xffff0000u));\
        atomicAdd((row) + 2, __uint_as_float((u).y << 16));        \
        atomicAdd((row) + 3, __uint_as_float((u).y & 0xffff0000u));\
        atomicAdd((row) + 4, __uint_as_float((u).z << 16));        \
        atomicAdd((row) + 5, __uint_as_float((u).z & 0xffff0000u));\
        atomicAdd((row) + 6, __uint_as_float((u).w << 16));        \
        atomicAdd((row) + 7, __uint_as_float((u).w & 0xffff0000u));

    int e = base + g;
    const int lim = base + cnt;
    for (; e + 64 < lim; e += 128) {
        unsigned w0 = binned[e];
        unsigned w1 = binned[e + 64];
        uint4 u0 = *(const uint4*)(feat + (size_t)(w0 & 0x1FFFFu) * 64 + p * 8);
        uint4 u1 = *(const uint4*)(feat + (size_t)(w1 & 0x1FFFFu) * 64 + p * 8);
        float* r0 = acc + (w0 >> 17) * 68 + p * 8;
        float* r1 = acc + (w1 >> 17) * 68 + p * 8;
        ACC8(r0, u0)
        ACC8(r1, u1)
        if (p == 0) {
            atomicAdd(&ldeg[w0 >> 17], 1);
            atomicAdd(&ldeg[w1 >> 17], 1);
        }
    }
    if (e < lim) {
        unsigned w0 = binned[e];
        uint4 u0 = *(const uint4*)(feat + (size_t)(w0 & 0x1FFFFu) * 64 + p * 8);
        float* r0 = acc + (w0 >> 17) * 68 + p * 8;
        ACC8(r0, u0)
        if (p == 0) atomicAdd(&ldeg[w0 >> 17], 1);
    }
    #undef ACC8

    __syncthreads();
    // epilogue: thread t -> node_local t>>2, feature quad (t&3)*16
    const int nl = t >> 2;
    const int node = b * 128 + nl;
    if (node < NN) {
        float iv = 1.0f / fmaxf((float)ldeg[nl], 1.0f);
        const float* row = acc + nl * 68 + (t & 3) * 16;
        union { bf16x8 v; unsigned short us[8]; } c0, c1;
        #pragma unroll
        for (int i = 0; i < 8; ++i) c0.us[i] = f2bf(row[i] * iv);
        #pragma unroll
        for (int i = 0; i < 8; ++i) c1.us[i] = f2bf(row[8 + i] * iv);
        unsigned short* dp = A + (size_t)node * 64 + (t & 3) * 16;
        *(bf16x8*)(dp) = c0.v;
        *(bf16x8*)(dp + 8) = c1.v;
    }
}

// ---- Node transform via bf16 MFMA, LDS-free --------------------------------
__global__ __launch_bounds__(256) void k_gemm(const unsigned short* __restrict__ Ab,
                                              const unsigned short* __restrict__ Xb,
                                              const unsigned short* __restrict__ Wc,
                                              const float* __restrict__ bias,
                                              float* __restrict__ Cf,
                                              unsigned short* __restrict__ Cb) {
    const int t = threadIdx.x;
    const int w = t >> 6;
    const int l = t & 63;
    const int cn = l & 15;
    const int ks = l >> 4;
    const int n0 = blockIdx.x * 64 + w * 16;

    int arow = n0 + cn;
    int aclamp = (arow < NN) ? arow : 0;

    f32x4 acc0 = {0.f, 0.f, 0.f, 0.f};
    f32x4 acc1 = {0.f, 0.f, 0.f, 0.f};
    f32x4 acc2 = {0.f, 0.f, 0.f, 0.f};
    f32x4 acc3 = {0.f, 0.f, 0.f, 0.f};

    #pragma unroll
    for (int kb = 0; kb < 4; ++kb) {
        const unsigned short* ap = (kb < 2)
            ? (Ab + (size_t)aclamp * 64 + kb * 32 + ks * 8)
            : (Xb + (size_t)aclamp * 64 + (kb - 2) * 32 + ks * 8);
        bf16x8 aa = *(const bf16x8*)ap;
        const unsigned short* wb = Wc + cn * 128 + kb * 32 + ks * 8;
        bf16x8 b0 = *(const bf16x8*)(wb);
        bf16x8 b1 = *(const bf16x8*)(wb + 16 * 128);
        bf16x8 b2 = *(const bf16x8*)(wb + 32 * 128);
        bf16x8 b3 = *(const bf16x8*)(wb + 48 * 128);
        acc0 = __builtin_amdgcn_mfma_f32_16x16x32_bf16(aa, b0, acc0, 0, 0, 0);
        acc1 = __builtin_amdgcn_mfma_f32_16x16x32_bf16(aa, b1, acc1, 0, 0, 0);
        acc2 = __builtin_amdgcn_mfma_f32_16x16x32_bf16(aa, b2, acc2, 0, 0, 0);
        acc3 = __builtin_amdgcn_mfma_f32_16x16x32_bf16(aa, b3, acc3, 0, 0, 0);
    }

    #pragma unroll
    for (int f = 0; f < 4; ++f) {
        f32x4 av = (f == 0) ? acc0 : (f == 1) ? acc1 : (f == 2) ? acc2 : acc3;
        float bv = bias[f * 16 + cn];
        #pragma unroll
        for (int r = 0; r < 4; ++r) {
            int node = n0 + ks * 4 + r;
            if (node < NN) {
                float val = av[r] + bv;
                if (Cb) Cb[(size_t)node * 64 + f * 16 + cn] = f2bf(val);
                else    Cf[(size_t)node * 64 + f * 16 + cn] = val;
            }
        }
    }
}

// ---- host ------------------------------------------------------------------

extern "C" void kernel_launch(void* const* d_in, const int* in_sizes, int n_in,
                              void* d_out, int out_size, void* d_ws, size_t ws_size,
                              hipStream_t stream) {
    const float* x   = (const float*)d_in[0];
    const int*   ei  = (const int*)d_in[1];
    const int*   src = ei;
    const int*   dst = ei + NE;
    const float* Wl1 = (const float*)d_in[2];
    const float* b1  = (const float*)d_in[3];
    const float* Wr1 = (const float*)d_in[4];
    const float* Wl2 = (const float*)d_in[5];
    const float* b2  = (const float*)d_in[6];
    const float* Wr2 = (const float*)d_in[7];
    float* out = (float*)d_out;

    char* ws = (char*)d_ws;
    size_t off = 0;
    auto alloc = [&](size_t bytes) {
        void* p = ws + off;
        off = (off + bytes + 255) & ~(size_t)255;
        return p;
    };
    unsigned short* A      = (unsigned short*)alloc(2 * (size_t)NN * 64);    // 12.8 MB
    unsigned short* xb     = (unsigned short*)alloc(2 * (size_t)NN * 64);    // 12.8 MB
    unsigned short* h1b    = (unsigned short*)alloc(2 * (size_t)NN * 64);    // 12.8 MB
    unsigned*       binned = (unsigned*)alloc(sizeof(unsigned) * NBK * BCAP);// 8.4 MB
    int*            gcur   = (int*)alloc(sizeof(int) * NBK);
    unsigned short* Wc1    = (unsigned short*)alloc(2 * 64 * 128);
    unsigned short* Wc2    = (unsigned short*)alloc(2 * 64 * 128);

    // one-time prep (reused by both layers)
    k_init<<<(NBK + 255) / 256, 256, 0, stream>>>(gcur);
    k_wcvt<<<16, 256, 0, stream>>>(Wl1, Wr1, Wl2, Wr2, Wc1, Wc2);
    k_xcvt<<<(NN * 64 / 8 + 255) / 256, 256, 0, stream>>>(x, xb);
    k_bin <<<BIN_BLKS, 256, 0, stream>>>(src, dst, gcur, binned);

    // layer 1: h1b (bf16) = [agg(xb) | xb] @ Wc1^T + b1
    k_agg <<<NBK, 512, 0, stream>>>(xb, binned, gcur, A);
    k_gemm<<<(NN + 63) / 64, 256, 0, stream>>>(A, xb, Wc1, b1, (float*)nullptr, h1b);

    // layer 2: out (f32) = [agg(h1b) | h1b] @ Wc2^T + b2
    k_agg <<<NBK, 512, 0, stream>>>(h1b, binned, gcur, A);
    k_gemm<<<(NN + 63) / 64, 256, 0, stream>>>(A, h1b, Wc2, b2, out, (unsigned short*)nullptr);
}

// Round 7
// 165.444 us; speedup vs baseline: 8.8115x; 8.8115x over previous
//
#include <hip/hip_runtime.h>
#include <hip/hip_bf16.h>

#define NN 100000
#define NE 1600000
#define NB 196            // dst-range buckets of 512 nodes
#define BCAP 9216         // padded bucket capacity (mean 8192, sd ~90 -> +11 sigma)
#define BIN_CHUNK 8192
#define BIN_BLKS ((NE + BIN_CHUNK - 1) / BIN_CHUNK)   // 196

typedef __attribute__((ext_vector_type(8))) short bf16x8;
typedef __attribute__((ext_vector_type(4))) float f32x4;

__device__ inline unsigned short f2bf(float f) {
    union { __hip_bfloat16 h; unsigned short u; } c;
    c.h = __float2bfloat16(f);
    return c.u;
}

// ---- bucket cursors init ---------------------------------------------------
__global__ void k_init(int* __restrict__ gcur) {
    int t = threadIdx.x;
    if (t < NB) gcur[t] = t * BCAP;
}

// ---- weights -> bf16, Wcat[fo][0:64]=Wl[fo][:], [64:128]=Wr[fo][:] ---------
__global__ void k_wcvt(const float* __restrict__ Wl1, const float* __restrict__ Wr1,
                       const float* __restrict__ Wl2, const float* __restrict__ Wr2,
                       unsigned short* __restrict__ Wc1, unsigned short* __restrict__ Wc2) {
    int e = blockIdx.x * 256 + threadIdx.x;
    if (e < 4096) {
        int fo = e >> 6, k = e & 63;
        Wc1[fo * 128 + k]      = f2bf(Wl1[e]);
        Wc1[fo * 128 + 64 + k] = f2bf(Wr1[e]);
        Wc2[fo * 128 + k]      = f2bf(Wl2[e]);
        Wc2[fo * 128 + 64 + k] = f2bf(Wr2[e]);
    }
}

// ---- x (f32) -> bf16 table --------------------------------------------------
__global__ __launch_bounds__(256) void k_xcvt(const float* __restrict__ x,
                                              unsigned short* __restrict__ xb) {
    int i = blockIdx.x * 256 + threadIdx.x;     // 8 elements per thread
    if (i >= NN * 64 / 8) return;
    const float4* p = (const float4*)(x + (size_t)i * 8);
    float4 v0 = p[0], v1 = p[1];
    union { bf16x8 v; unsigned short u[8]; } c;
    c.u[0] = f2bf(v0.x); c.u[1] = f2bf(v0.y); c.u[2] = f2bf(v0.z); c.u[3] = f2bf(v0.w);
    c.u[4] = f2bf(v1.x); c.u[5] = f2bf(v1.y); c.u[6] = f2bf(v1.z); c.u[7] = f2bf(v1.w);
    *(bf16x8*)(xb + (size_t)i * 8) = c.v;
}

// ---- bin edges by dst>>9 into padded bucket regions ------------------------
__global__ __launch_bounds__(256) void k_bin(const int* __restrict__ src,
                                             const int* __restrict__ dst,
                                             int* __restrict__ gcur,
                                             unsigned* __restrict__ binned) {
    __shared__ int hist[NB];
    __shared__ int base[NB];
    __shared__ int lcur[NB];
    const int t = threadIdx.x;
    const int e0 = blockIdx.x * BIN_CHUNK;
    const int n = min(BIN_CHUNK, NE - e0);
    for (int i = t; i < NB; i += 256) { hist[i] = 0; lcur[i] = 0; }
    __syncthreads();
    for (int i = t; i < n; i += 256)
        atomicAdd(&hist[dst[e0 + i] >> 9], 1);
    __syncthreads();
    for (int i = t; i < NB; i += 256) {
        int h = hist[i];
        base[i] = h ? atomicAdd(&gcur[i], h) : 0;
    }
    __syncthreads();
    for (int i = t; i < n; i += 256) {
        int d = dst[e0 + i];
        int s = src[e0 + i];
        int b = d >> 9;
        int p = base[b] + atomicAdd(&lcur[b], 1);
        binned[p] = ((unsigned)(d & 511) << 17) | (unsigned)s;
    }
}

// ---- per-bucket CSR finalize -----------------------------------------------
__global__ __launch_bounds__(256) void k_csr(const int* __restrict__ gcur,
                                             unsigned* __restrict__ binned,
                                             int2* __restrict__ noff,
                                             float* __restrict__ inv) {
    __shared__ unsigned buf[BCAP];
    __shared__ int h[512];
    __shared__ int off[512];
    __shared__ int lcur[512];
    __shared__ int s[256];
    const int b = blockIdx.x;
    const int t = threadIdx.x;
    const int base = b * BCAP;
    const int cnt = min(gcur[b] - base, BCAP);
    for (int i = t; i < 512; i += 256) h[i] = 0;
    __syncthreads();
    for (int i = t; i < cnt; i += 256) {
        unsigned v = binned[base + i];
        buf[i] = v;
        atomicAdd(&h[v >> 17], 1);
    }
    __syncthreads();
    int a0 = h[2 * t], a1 = h[2 * t + 1];
    s[t] = a0 + a1;
    __syncthreads();
    #pragma unroll
    for (int o = 1; o < 256; o <<= 1) {
        int u = (t >= o) ? s[t - o] : 0;
        __syncthreads();
        s[t] += u;
        __syncthreads();
    }
    int ex = s[t] - (a0 + a1);
    off[2 * t] = ex;          lcur[2 * t] = ex;
    off[2 * t + 1] = ex + a0; lcur[2 * t + 1] = ex + a0;
    __syncthreads();
    for (int i = t; i < cnt; i += 256) {
        unsigned v = buf[i];
        int dl = v >> 17;
        int p = atomicAdd(&lcur[dl], 1);
        binned[base + p] = v & 0x1FFFFu;
    }
    #pragma unroll
    for (int q = 0; q < 2; ++q) {
        int l = 2 * t + q;
        int node = b * 512 + l;
        if (node < NN) {
            int st = base + off[l];
            noff[node] = make_int2(st, st + h[l]);
            inv[node] = 1.0f / fmaxf((float)h[l], 1.0f);
        }
    }
}

// ---- Aggregation: 8-lane group per node, lane owns 8 features --------------
// Group walks the node's edge list with 4-deep unrolled 16 B gathers; lane p
// accumulates features [8p,8p+8) in registers -> no cross-lane reduce.
// 8 groups/wave -> up to 32 outstanding gathers/wave. Output A bf16 [NN][64].
__global__ __launch_bounds__(512) void k_agg(const unsigned short* __restrict__ feat,
                                             const int2* __restrict__ noff,
                                             const unsigned* __restrict__ csr,
                                             const float* __restrict__ inv,
                                             unsigned short* __restrict__ A) {
    int gid = (blockIdx.x * 512 + threadIdx.x) >> 3;   // node index
    int p = threadIdx.x & 7;
    if (gid >= NN) return;
    int2 oe = noff[gid];
    int beg = oe.x, end = oe.y;
    float a[8] = {0.f, 0.f, 0.f, 0.f, 0.f, 0.f, 0.f, 0.f};

    #define UNPK(uu, k)                                        \
        a[2*(k)]   += __uint_as_float((uu) << 16);             \
        a[2*(k)+1] += __uint_as_float((uu) & 0xffff0000u);

    int j = beg;
    for (; j + 4 <= end; j += 4) {
        unsigned s0 = csr[j], s1 = csr[j + 1], s2 = csr[j + 2], s3 = csr[j + 3];
        uint4 u0 = *(const uint4*)(feat + (size_t)s0 * 64 + p * 8);
        uint4 u1 = *(const uint4*)(feat + (size_t)s1 * 64 + p * 8);
        uint4 u2 = *(const uint4*)(feat + (size_t)s2 * 64 + p * 8);
        uint4 u3 = *(const uint4*)(feat + (size_t)s3 * 64 + p * 8);
        UNPK(u0.x, 0) UNPK(u0.y, 1) UNPK(u0.z, 2) UNPK(u0.w, 3)
        UNPK(u1.x, 0) UNPK(u1.y, 1) UNPK(u1.z, 2) UNPK(u1.w, 3)
        UNPK(u2.x, 0) UNPK(u2.y, 1) UNPK(u2.z, 2) UNPK(u2.w, 3)
        UNPK(u3.x, 0) UNPK(u3.y, 1) UNPK(u3.z, 2) UNPK(u3.w, 3)
    }
    for (; j < end; ++j) {
        uint4 u0 = *(const uint4*)(feat + (size_t)csr[j] * 64 + p * 8);
        UNPK(u0.x, 0) UNPK(u0.y, 1) UNPK(u0.z, 2) UNPK(u0.w, 3)
    }
    #undef UNPK

    float iv = inv[gid];
    union { bf16x8 v; unsigned short u[8]; } c;
    #pragma unroll
    for (int e = 0; e < 8; ++e) c.u[e] = f2bf(a[e] * iv);
    *(bf16x8*)(A + (size_t)gid * 64 + p * 8) = c.v;
}

// ---- Node transform via bf16 MFMA, LDS-free --------------------------------
__global__ __launch_bounds__(256) void k_gemm(const unsigned short* __restrict__ Ab,
                                              const unsigned short* __restrict__ Xb,
                                              const unsigned short* __restrict__ Wc,
                                              const float* __restrict__ bias,
                                              float* __restrict__ Cf,
                                              unsigned short* __restrict__ Cb) {
    const int t = threadIdx.x;
    const int w = t >> 6;
    const int l = t & 63;
    const int cn = l & 15;        // A-row / B-col / C-col selector
    const int ks = l >> 4;        // k-subgroup 0..3
    const int n0 = blockIdx.x * 64 + w * 16;

    int arow = n0 + cn;
    int aclamp = (arow < NN) ? arow : 0;

    f32x4 acc0 = {0.f, 0.f, 0.f, 0.f};
    f32x4 acc1 = {0.f, 0.f, 0.f, 0.f};
    f32x4 acc2 = {0.f, 0.f, 0.f, 0.f};
    f32x4 acc3 = {0.f, 0.f, 0.f, 0.f};

    #pragma unroll
    for (int kb = 0; kb < 4; ++kb) {
        const unsigned short* ap = (kb < 2)
            ? (Ab + (size_t)aclamp * 64 + kb * 32 + ks * 8)
            : (Xb + (size_t)aclamp * 64 + (kb - 2) * 32 + ks * 8);
        bf16x8 aa = *(const bf16x8*)ap;
        const unsigned short* wb = Wc + cn * 128 + kb * 32 + ks * 8;
        bf16x8 b0 = *(const bf16x8*)(wb);
        bf16x8 b1 = *(const bf16x8*)(wb + 16 * 128);
        bf16x8 b2 = *(const bf16x8*)(wb + 32 * 128);
        bf16x8 b3 = *(const bf16x8*)(wb + 48 * 128);
        acc0 = __builtin_amdgcn_mfma_f32_16x16x32_bf16(aa, b0, acc0, 0, 0, 0);
        acc1 = __builtin_amdgcn_mfma_f32_16x16x32_bf16(aa, b1, acc1, 0, 0, 0);
        acc2 = __builtin_amdgcn_mfma_f32_16x16x32_bf16(aa, b2, acc2, 0, 0, 0);
        acc3 = __builtin_amdgcn_mfma_f32_16x16x32_bf16(aa, b3, acc3, 0, 0, 0);
    }

    // C/D layout: col = lane&15, row = (lane>>4)*4 + r
    #pragma unroll
    for (int f = 0; f < 4; ++f) {
        f32x4 av = (f == 0) ? acc0 : (f == 1) ? acc1 : (f == 2) ? acc2 : acc3;
        float bv = bias[f * 16 + cn];
        #pragma unroll
        for (int r = 0; r < 4; ++r) {
            int node = n0 + ks * 4 + r;
            if (node < NN) {
                float val = av[r] + bv;
                if (Cb) Cb[(size_t)node * 64 + f * 16 + cn] = f2bf(val);
                else    Cf[(size_t)node * 64 + f * 16 + cn] = val;
            }
        }
    }
}

// ---- host ------------------------------------------------------------------

extern "C" void kernel_launch(void* const* d_in, const int* in_sizes, int n_in,
                              void* d_out, int out_size, void* d_ws, size_t ws_size,
                              hipStream_t stream) {
    const float* x   = (const float*)d_in[0];
    const int*   ei  = (const int*)d_in[1];
    const int*   src = ei;
    const int*   dst = ei + NE;
    const float* Wl1 = (const float*)d_in[2];
    const float* b1  = (const float*)d_in[3];
    const float* Wr1 = (const float*)d_in[4];
    const float* Wl2 = (const float*)d_in[5];
    const float* b2  = (const float*)d_in[6];
    const float* Wr2 = (const float*)d_in[7];
    float* out = (float*)d_out;

    char* ws = (char*)d_ws;
    size_t off = 0;
    auto alloc = [&](size_t bytes) {
        void* p = ws + off;
        off = (off + bytes + 255) & ~(size_t)255;
        return p;
    };
    unsigned short* A      = (unsigned short*)alloc(2 * (size_t)NN * 64);   // 12.8 MB
    unsigned short* xb     = (unsigned short*)alloc(2 * (size_t)NN * 64);   // 12.8 MB
    unsigned short* h1b    = (unsigned short*)alloc(2 * (size_t)NN * 64);   // 12.8 MB
    unsigned*       binned = (unsigned*)alloc(sizeof(unsigned) * NB * BCAP);// 7.2 MB
    int2*           noff   = (int2*)alloc(sizeof(int2) * NN);
    float*          inv    = (float*)alloc(sizeof(float) * NN);
    int*            gcur   = (int*)alloc(sizeof(int) * NB);
    unsigned short* Wc1    = (unsigned short*)alloc(2 * 64 * 128);
    unsigned short* Wc2    = (unsigned short*)alloc(2 * 64 * 128);

    // one-time prep (reused by both layers)
    k_init<<<1, 256, 0, stream>>>(gcur);
    k_wcvt<<<16, 256, 0, stream>>>(Wl1, Wr1, Wl2, Wr2, Wc1, Wc2);
    k_xcvt<<<(NN * 64 / 8 + 255) / 256, 256, 0, stream>>>(x, xb);
    k_bin <<<BIN_BLKS, 256, 0, stream>>>(src, dst, gcur, binned);
    k_csr <<<NB, 256, 0, stream>>>(gcur, binned, noff, inv);

    // layer 1: h1b (bf16) = [agg(xb) | xb] @ Wc1^T + b1
    k_agg <<<((size_t)NN * 8 + 511) / 512, 512, 0, stream>>>(xb, noff, binned, inv, A);
    k_gemm<<<(NN + 63) / 64, 256, 0, stream>>>(A, xb, Wc1, b1, (float*)nullptr, h1b);

    // layer 2: out (f32) = [agg(h1b) | h1b] @ Wc2^T + b2
    k_agg <<<((size_t)NN * 8 + 511) / 512, 512, 0, stream>>>(h1b, noff, binned, inv, A);
    k_gemm<<<(NN + 63) / 64, 256, 0, stream>>>(A, h1b, Wc2, b2, out, (unsigned short*)nullptr);
}

// Round 8
// 141.680 us; speedup vs baseline: 10.2894x; 1.1677x over previous
//
#include <hip/hip_runtime.h>
#include <hip/hip_bf16.h>

#define NN 100000
#define NE 1600000
#define NB 196            // dst-range buckets of 512 nodes
#define BCAP 9216         // padded bucket capacity (mean 8192, sd ~90 -> +11 sigma)
#define BIN_CHUNK 8192
#define BIN_BLKS ((NE + BIN_CHUNK - 1) / BIN_CHUNK)   // 196

typedef __attribute__((ext_vector_type(8))) short bf16x8;
typedef __attribute__((ext_vector_type(4))) float f32x4;

__device__ inline unsigned short f2bf(float f) {
    union { __hip_bfloat16 h; unsigned short u; } c;
    c.h = __float2bfloat16(f);
    return c.u;
}

// ---- fused prep: gcur init + weight cvt + x cvt ----------------------------
__global__ __launch_bounds__(256) void k_prep(const float* __restrict__ x,
                                              unsigned short* __restrict__ xb,
                                              const float* __restrict__ Wl1,
                                              const float* __restrict__ Wr1,
                                              const float* __restrict__ Wl2,
                                              const float* __restrict__ Wr2,
                                              unsigned short* __restrict__ Wc1,
                                              unsigned short* __restrict__ Wc2,
                                              int* __restrict__ gcur) {
    int i = blockIdx.x * 256 + threadIdx.x;
    if (i < NB) gcur[i] = i * BCAP;
    if (i < 4096) {
        int fo = i >> 6, k = i & 63;
        Wc1[fo * 128 + k]      = f2bf(Wl1[i]);
        Wc1[fo * 128 + 64 + k] = f2bf(Wr1[i]);
        Wc2[fo * 128 + k]      = f2bf(Wl2[i]);
        Wc2[fo * 128 + 64 + k] = f2bf(Wr2[i]);
    }
    if (i < NN * 64 / 8) {
        const float4* p = (const float4*)(x + (size_t)i * 8);
        float4 v0 = p[0], v1 = p[1];
        union { bf16x8 v; unsigned short u[8]; } c;
        c.u[0] = f2bf(v0.x); c.u[1] = f2bf(v0.y); c.u[2] = f2bf(v0.z); c.u[3] = f2bf(v0.w);
        c.u[4] = f2bf(v1.x); c.u[5] = f2bf(v1.y); c.u[6] = f2bf(v1.z); c.u[7] = f2bf(v1.w);
        *(bf16x8*)(xb + (size_t)i * 8) = c.v;
    }
}

// ---- bin edges by dst>>9 into padded bucket regions (int4 vectorized) ------
__global__ __launch_bounds__(256) void k_bin(const int* __restrict__ src,
                                             const int* __restrict__ dst,
                                             int* __restrict__ gcur,
                                             unsigned* __restrict__ binned) {
    __shared__ int hist[NB];
    __shared__ int base[NB];
    __shared__ int lcur[NB];
    const int t = threadIdx.x;
    const int e0 = blockIdx.x * BIN_CHUNK;
    const int n4 = min(BIN_CHUNK, NE - e0) >> 2;    // always divisible by 4
    for (int i = t; i < NB; i += 256) { hist[i] = 0; lcur[i] = 0; }
    __syncthreads();
    const int4* d4p = (const int4*)(dst + e0);
    const int4* s4p = (const int4*)(src + e0);
    for (int i = t; i < n4; i += 256) {
        int4 d = d4p[i];
        atomicAdd(&hist[d.x >> 9], 1);
        atomicAdd(&hist[d.y >> 9], 1);
        atomicAdd(&hist[d.z >> 9], 1);
        atomicAdd(&hist[d.w >> 9], 1);
    }
    __syncthreads();
    for (int i = t; i < NB; i += 256) {
        int h = hist[i];
        base[i] = h ? atomicAdd(&gcur[i], h) : 0;
    }
    __syncthreads();
    for (int i = t; i < n4; i += 256) {
        int4 d = d4p[i];
        int4 s = s4p[i];
        #define PLACE(dd, ss) {                                         \
            int b = (dd) >> 9;                                          \
            int p = base[b] + atomicAdd(&lcur[b], 1);                   \
            binned[p] = ((unsigned)((dd) & 511) << 17) | (unsigned)(ss);}
        PLACE(d.x, s.x) PLACE(d.y, s.y) PLACE(d.z, s.z) PLACE(d.w, s.w)
        #undef PLACE
    }
}

// ---- per-bucket CSR finalize -----------------------------------------------
__global__ __launch_bounds__(256) void k_csr(const int* __restrict__ gcur,
                                             unsigned* __restrict__ binned,
                                             int2* __restrict__ noff,
                                             float* __restrict__ inv) {
    __shared__ unsigned buf[BCAP];
    __shared__ int h[512];
    __shared__ int off[512];
    __shared__ int lcur[512];
    __shared__ int s[256];
    const int b = blockIdx.x;
    const int t = threadIdx.x;
    const int base = b * BCAP;
    const int cnt = min(gcur[b] - base, BCAP);
    for (int i = t; i < 512; i += 256) h[i] = 0;
    __syncthreads();
    for (int i = t; i < cnt; i += 256) {
        unsigned v = binned[base + i];
        buf[i] = v;
        atomicAdd(&h[v >> 17], 1);
    }
    __syncthreads();
    int a0 = h[2 * t], a1 = h[2 * t + 1];
    s[t] = a0 + a1;
    __syncthreads();
    #pragma unroll
    for (int o = 1; o < 256; o <<= 1) {
        int u = (t >= o) ? s[t - o] : 0;
        __syncthreads();
        s[t] += u;
        __syncthreads();
    }
    int ex = s[t] - (a0 + a1);
    off[2 * t] = ex;          lcur[2 * t] = ex;
    off[2 * t + 1] = ex + a0; lcur[2 * t + 1] = ex + a0;
    __syncthreads();
    for (int i = t; i < cnt; i += 256) {
        unsigned v = buf[i];
        int dl = v >> 17;
        int p = atomicAdd(&lcur[dl], 1);
        binned[base + p] = v & 0x1FFFFu;
    }
    #pragma unroll
    for (int q = 0; q < 2; ++q) {
        int l = 2 * t + q;
        int node = b * 512 + l;
        if (node < NN) {
            int st = base + off[l];
            noff[node] = make_int2(st, st + h[l]);
            inv[node] = 1.0f / fmaxf((float)h[l], 1.0f);
        }
    }
}

// ---- Fused layer: aggregate 64-node tile (8 lanes/node, registers) to LDS,
//      then 8-wave MFMA transform; self-path read from the same feat table.
//      Output: bf16 to Cb if Cb!=0 else f32 to Cf.
__global__ __launch_bounds__(512) void k_fused(const unsigned short* __restrict__ feat,
                                               const int2* __restrict__ noff,
                                               const unsigned* __restrict__ csr,
                                               const float* __restrict__ inv,
                                               const unsigned short* __restrict__ Wc,
                                               const float* __restrict__ bias,
                                               float* __restrict__ Cf,
                                               unsigned short* __restrict__ Cb) {
    __shared__ unsigned short sA[64 * 72];   // stride 72 shorts = 144 B (16B-mult)
    const int t = threadIdx.x;
    const int n0 = blockIdx.x * 64;

    // ---- phase 1: aggregation ----
    {
        const int g = t >> 3;        // local node 0..63
        const int p = t & 7;         // feature octet
        const int node = n0 + g;
        float a[8] = {0.f, 0.f, 0.f, 0.f, 0.f, 0.f, 0.f, 0.f};
        float iv = 0.f;
        if (node < NN) {
            int2 oe = noff[node];
            int beg = oe.x, end = oe.y;

            #define UNPK(uu, k)                                        \
                a[2*(k)]   += __uint_as_float((uu) << 16);             \
                a[2*(k)+1] += __uint_as_float((uu) & 0xffff0000u);

            int j = beg;
            for (; j + 4 <= end; j += 4) {
                unsigned s0 = csr[j], s1 = csr[j + 1], s2 = csr[j + 2], s3 = csr[j + 3];
                uint4 u0 = *(const uint4*)(feat + (size_t)s0 * 64 + p * 8);
                uint4 u1 = *(const uint4*)(feat + (size_t)s1 * 64 + p * 8);
                uint4 u2 = *(const uint4*)(feat + (size_t)s2 * 64 + p * 8);
                uint4 u3 = *(const uint4*)(feat + (size_t)s3 * 64 + p * 8);
                UNPK(u0.x, 0) UNPK(u0.y, 1) UNPK(u0.z, 2) UNPK(u0.w, 3)
                UNPK(u1.x, 0) UNPK(u1.y, 1) UNPK(u1.z, 2) UNPK(u1.w, 3)
                UNPK(u2.x, 0) UNPK(u2.y, 1) UNPK(u2.z, 2) UNPK(u2.w, 3)
                UNPK(u3.x, 0) UNPK(u3.y, 1) UNPK(u3.z, 2) UNPK(u3.w, 3)
            }
            for (; j < end; ++j) {
                uint4 u0 = *(const uint4*)(feat + (size_t)csr[j] * 64 + p * 8);
                UNPK(u0.x, 0) UNPK(u0.y, 1) UNPK(u0.z, 2) UNPK(u0.w, 3)
            }
            #undef UNPK
            iv = inv[node];
        }
        union { bf16x8 v; unsigned short u[8]; } c;
        #pragma unroll
        for (int e = 0; e < 8; ++e) c.u[e] = f2bf(a[e] * iv);
        *(bf16x8*)(&sA[g * 72 + p * 8]) = c.v;
    }
    __syncthreads();

    // ---- phase 2: MFMA transform of the 64-node tile ----
    const int w = t >> 6;        // wave 0..7
    const int l = t & 63;
    const int cn = l & 15;       // A-row / B-col selector
    const int ks = l >> 4;       // k-subgroup
    const int s = w & 3;         // node strip (16 nodes)
    const int h = w >> 2;        // fo half (32 cols)
    const int lrow = s * 16 + cn;
    const int arow = n0 + lrow;
    const int aclamp = (arow < NN) ? arow : 0;

    f32x4 acc0 = {0.f, 0.f, 0.f, 0.f};
    f32x4 acc1 = {0.f, 0.f, 0.f, 0.f};

    #pragma unroll
    for (int kb = 0; kb < 4; ++kb) {
        bf16x8 aa;
        if (kb < 2) aa = *(const bf16x8*)(&sA[lrow * 72 + kb * 32 + ks * 8]);
        else        aa = *(const bf16x8*)(feat + (size_t)aclamp * 64 + (kb - 2) * 32 + ks * 8);
        const unsigned short* wb = Wc + cn * 128 + kb * 32 + ks * 8;
        bf16x8 b0 = *(const bf16x8*)(wb + (size_t)(2 * h) * 16 * 128);
        bf16x8 b1 = *(const bf16x8*)(wb + (size_t)(2 * h + 1) * 16 * 128);
        acc0 = __builtin_amdgcn_mfma_f32_16x16x32_bf16(aa, b0, acc0, 0, 0, 0);
        acc1 = __builtin_amdgcn_mfma_f32_16x16x32_bf16(aa, b1, acc1, 0, 0, 0);
    }

    // C/D layout: col = lane&15, row = (lane>>4)*4 + r
    #pragma unroll
    for (int fb = 0; fb < 2; ++fb) {
        f32x4 av = fb ? acc1 : acc0;
        int f = 2 * h + fb;
        float bv = bias[f * 16 + cn];
        #pragma unroll
        for (int r = 0; r < 4; ++r) {
            int node = n0 + s * 16 + ks * 4 + r;
            if (node < NN) {
                float val = av[r] + bv;
                if (Cb) Cb[(size_t)node * 64 + f * 16 + cn] = f2bf(val);
                else    Cf[(size_t)node * 64 + f * 16 + cn] = val;
            }
        }
    }
}

// ---- host ------------------------------------------------------------------

extern "C" void kernel_launch(void* const* d_in, const int* in_sizes, int n_in,
                              void* d_out, int out_size, void* d_ws, size_t ws_size,
                              hipStream_t stream) {
    const float* x   = (const float*)d_in[0];
    const int*   ei  = (const int*)d_in[1];
    const int*   src = ei;
    const int*   dst = ei + NE;
    const float* Wl1 = (const float*)d_in[2];
    const float* b1  = (const float*)d_in[3];
    const float* Wr1 = (const float*)d_in[4];
    const float* Wl2 = (const float*)d_in[5];
    const float* b2  = (const float*)d_in[6];
    const float* Wr2 = (const float*)d_in[7];
    float* out = (float*)d_out;

    char* ws = (char*)d_ws;
    size_t off = 0;
    auto alloc = [&](size_t bytes) {
        void* p = ws + off;
        off = (off + bytes + 255) & ~(size_t)255;
        return p;
    };
    unsigned short* xb     = (unsigned short*)alloc(2 * (size_t)NN * 64);   // 12.8 MB
    unsigned short* h1b    = (unsigned short*)alloc(2 * (size_t)NN * 64);   // 12.8 MB
    unsigned*       binned = (unsigned*)alloc(sizeof(unsigned) * NB * BCAP);// 7.2 MB
    int2*           noff   = (int2*)alloc(sizeof(int2) * NN);
    float*          inv    = (float*)alloc(sizeof(float) * NN);
    int*            gcur   = (int*)alloc(sizeof(int) * NB);
    unsigned short* Wc1    = (unsigned short*)alloc(2 * 64 * 128);
    unsigned short* Wc2    = (unsigned short*)alloc(2 * 64 * 128);

    // prep (gcur + weights + x->bf16), then CSR build — reused by both layers
    k_prep<<<(NN * 64 / 8 + 255) / 256, 256, 0, stream>>>(x, xb, Wl1, Wr1, Wl2, Wr2,
                                                          Wc1, Wc2, gcur);
    k_bin <<<BIN_BLKS, 256, 0, stream>>>(src, dst, gcur, binned);
    k_csr <<<NB, 256, 0, stream>>>(gcur, binned, noff, inv);

    // layer 1: h1b (bf16) = [agg(xb) | xb] @ Wc1^T + b1
    k_fused<<<(NN + 63) / 64, 512, 0, stream>>>(xb, noff, binned, inv, Wc1, b1,
                                                (float*)nullptr, h1b);
    // layer 2: out (f32) = [agg(h1b) | h1b] @ Wc2^T + b2
    k_fused<<<(NN + 63) / 64, 512, 0, stream>>>(h1b, noff, binned, inv, Wc2, b2,
                                                out, (unsigned short*)nullptr);
}

// Round 9
// 140.542 us; speedup vs baseline: 10.3727x; 1.0081x over previous
//
#include <hip/hip_runtime.h>
#include <hip/hip_bf16.h>

#define NN 100000
#define NE 1600000
#define NB 196            // dst-range buckets of 512 nodes
#define BCAP 9216         // padded bucket capacity (mean 8192, sd ~90 -> +11 sigma)
#define BIN_CHUNK 8192
#define BIN_BLKS ((NE + BIN_CHUNK - 1) / BIN_CHUNK)   // 196

typedef __attribute__((ext_vector_type(8))) short bf16x8;
typedef __attribute__((ext_vector_type(4))) float f32x4;

__device__ inline unsigned short f2bf(float f) {
    union { __hip_bfloat16 h; unsigned short u; } c;
    c.h = __float2bfloat16(f);
    return c.u;
}

// ---- fused prep: gcur init + weight cvt + x cvt ----------------------------
__global__ __launch_bounds__(256) void k_prep(const float* __restrict__ x,
                                              unsigned short* __restrict__ xb,
                                              const float* __restrict__ Wl1,
                                              const float* __restrict__ Wr1,
                                              const float* __restrict__ Wl2,
                                              const float* __restrict__ Wr2,
                                              unsigned short* __restrict__ Wc1,
                                              unsigned short* __restrict__ Wc2,
                                              int* __restrict__ gcur) {
    int i = blockIdx.x * 256 + threadIdx.x;
    if (i < NB) gcur[i] = i * BCAP;
    if (i < 4096) {
        int fo = i >> 6, k = i & 63;
        Wc1[fo * 128 + k]      = f2bf(Wl1[i]);
        Wc1[fo * 128 + 64 + k] = f2bf(Wr1[i]);
        Wc2[fo * 128 + k]      = f2bf(Wl2[i]);
        Wc2[fo * 128 + 64 + k] = f2bf(Wr2[i]);
    }
    if (i < NN * 64 / 8) {
        const float4* p = (const float4*)(x + (size_t)i * 8);
        float4 v0 = p[0], v1 = p[1];
        union { bf16x8 v; unsigned short u[8]; } c;
        c.u[0] = f2bf(v0.x); c.u[1] = f2bf(v0.y); c.u[2] = f2bf(v0.z); c.u[3] = f2bf(v0.w);
        c.u[4] = f2bf(v1.x); c.u[5] = f2bf(v1.y); c.u[6] = f2bf(v1.z); c.u[7] = f2bf(v1.w);
        *(bf16x8*)(xb + (size_t)i * 8) = c.v;
    }
}

// ---- bin edges by dst>>9 into padded bucket regions (int4 vectorized) ------
__global__ __launch_bounds__(256) void k_bin(const int* __restrict__ src,
                                             const int* __restrict__ dst,
                                             int* __restrict__ gcur,
                                             unsigned* __restrict__ binned) {
    __shared__ int hist[NB];
    __shared__ int base[NB];
    __shared__ int lcur[NB];
    const int t = threadIdx.x;
    const int e0 = blockIdx.x * BIN_CHUNK;
    const int n4 = min(BIN_CHUNK, NE - e0) >> 2;    // always divisible by 4
    for (int i = t; i < NB; i += 256) { hist[i] = 0; lcur[i] = 0; }
    __syncthreads();
    const int4* d4p = (const int4*)(dst + e0);
    const int4* s4p = (const int4*)(src + e0);
    for (int i = t; i < n4; i += 256) {
        int4 d = d4p[i];
        atomicAdd(&hist[d.x >> 9], 1);
        atomicAdd(&hist[d.y >> 9], 1);
        atomicAdd(&hist[d.z >> 9], 1);
        atomicAdd(&hist[d.w >> 9], 1);
    }
    __syncthreads();
    for (int i = t; i < NB; i += 256) {
        int h = hist[i];
        base[i] = h ? atomicAdd(&gcur[i], h) : 0;
    }
    __syncthreads();
    for (int i = t; i < n4; i += 256) {
        int4 d = d4p[i];
        int4 s = s4p[i];
        #define PLACE(dd, ss) {                                         \
            int b = (dd) >> 9;                                          \
            int p = base[b] + atomicAdd(&lcur[b], 1);                   \
            binned[p] = ((unsigned)((dd) & 511) << 17) | (unsigned)(ss);}
        PLACE(d.x, s.x) PLACE(d.y, s.y) PLACE(d.z, s.z) PLACE(d.w, s.w)
        #undef PLACE
    }
}

// ---- per-bucket CSR finalize -----------------------------------------------
__global__ __launch_bounds__(256) void k_csr(const int* __restrict__ gcur,
                                             unsigned* __restrict__ binned,
                                             int2* __restrict__ noff,
                                             float* __restrict__ inv) {
    __shared__ unsigned buf[BCAP];
    __shared__ int h[512];
    __shared__ int off[512];
    __shared__ int lcur[512];
    __shared__ int s[256];
    const int b = blockIdx.x;
    const int t = threadIdx.x;
    const int base = b * BCAP;
    const int cnt = min(gcur[b] - base, BCAP);
    for (int i = t; i < 512; i += 256) h[i] = 0;
    __syncthreads();
    for (int i = t; i < cnt; i += 256) {
        unsigned v = binned[base + i];
        buf[i] = v;
        atomicAdd(&h[v >> 17], 1);
    }
    __syncthreads();
    int a0 = h[2 * t], a1 = h[2 * t + 1];
    s[t] = a0 + a1;
    __syncthreads();
    #pragma unroll
    for (int o = 1; o < 256; o <<= 1) {
        int u = (t >= o) ? s[t - o] : 0;
        __syncthreads();
        s[t] += u;
        __syncthreads();
    }
    int ex = s[t] - (a0 + a1);
    off[2 * t] = ex;          lcur[2 * t] = ex;
    off[2 * t + 1] = ex + a0; lcur[2 * t + 1] = ex + a0;
    __syncthreads();
    for (int i = t; i < cnt; i += 256) {
        unsigned v = buf[i];
        int dl = v >> 17;
        int p = atomicAdd(&lcur[dl], 1);
        binned[base + p] = v & 0x1FFFFu;
    }
    #pragma unroll
    for (int q = 0; q < 2; ++q) {
        int l = 2 * t + q;
        int node = b * 512 + l;
        if (node < NN) {
            int st = base + off[l];
            noff[node] = make_int2(st, st + h[l]);
            inv[node] = 1.0f / fmaxf((float)h[l], 1.0f);
        }
    }
}

// ---- Fused layer: aggregate 64-node tile (8 lanes/node, registers) to LDS,
//      then 8-wave MFMA transform; self-path read from the same feat table.
//      Phase-1 gather loop is software-pipelined: next 4-edge batch issued
//      before current batch unpacks -> ~8 uint4 in flight per group.
__global__ __launch_bounds__(512) void k_fused(const unsigned short* __restrict__ feat,
                                               const int2* __restrict__ noff,
                                               const unsigned* __restrict__ csr,
                                               const float* __restrict__ inv,
                                               const unsigned short* __restrict__ Wc,
                                               const float* __restrict__ bias,
                                               float* __restrict__ Cf,
                                               unsigned short* __restrict__ Cb) {
    __shared__ unsigned short sA[64 * 72];   // stride 72 shorts = 144 B (16B-mult)
    const int t = threadIdx.x;
    const int n0 = blockIdx.x * 64;

    // ---- phase 1: aggregation ----
    {
        const int g = t >> 3;        // local node 0..63
        const int p = t & 7;         // feature octet
        const int node = n0 + g;
        float a[8] = {0.f, 0.f, 0.f, 0.f, 0.f, 0.f, 0.f, 0.f};
        float iv = 0.f;
        if (node < NN) {
            int2 oe = noff[node];
            int beg = oe.x, end = oe.y;
            iv = inv[node];

            #define UNPK(uu, k)                                        \
                a[2*(k)]   += __uint_as_float((uu) << 16);             \
                a[2*(k)+1] += __uint_as_float((uu) & 0xffff0000u);
            #define UNPK4(q0, q1, q2, q3)                              \
                UNPK(q0.x, 0) UNPK(q0.y, 1) UNPK(q0.z, 2) UNPK(q0.w, 3)\
                UNPK(q1.x, 0) UNPK(q1.y, 1) UNPK(q1.z, 2) UNPK(q1.w, 3)\
                UNPK(q2.x, 0) UNPK(q2.y, 1) UNPK(q2.z, 2) UNPK(q2.w, 3)\
                UNPK(q3.x, 0) UNPK(q3.y, 1) UNPK(q3.z, 2) UNPK(q3.w, 3)
            #define GATHER(s) (*(const uint4*)(feat + (size_t)(s) * 64 + p * 8))

            int j = beg;
            uint4 u0, u1, u2, u3;
            bool pending = false;
            if (j + 4 <= end) {
                u0 = GATHER(csr[j]);     u1 = GATHER(csr[j + 1]);
                u2 = GATHER(csr[j + 2]); u3 = GATHER(csr[j + 3]);
                j += 4;
                pending = true;
            }
            for (; j + 4 <= end; j += 4) {
                uint4 v0 = GATHER(csr[j]);     uint4 v1 = GATHER(csr[j + 1]);
                uint4 v2 = GATHER(csr[j + 2]); uint4 v3 = GATHER(csr[j + 3]);
                UNPK4(u0, u1, u2, u3)
                u0 = v0; u1 = v1; u2 = v2; u3 = v3;
            }
            if (pending) { UNPK4(u0, u1, u2, u3) }
            for (; j < end; ++j) {
                uint4 w0 = GATHER(csr[j]);
                UNPK(w0.x, 0) UNPK(w0.y, 1) UNPK(w0.z, 2) UNPK(w0.w, 3)
            }
            #undef GATHER
            #undef UNPK4
            #undef UNPK
        }
        union { bf16x8 v; unsigned short u[8]; } c;
        #pragma unroll
        for (int e = 0; e < 8; ++e) c.u[e] = f2bf(a[e] * iv);
        *(bf16x8*)(&sA[g * 72 + p * 8]) = c.v;
    }
    __syncthreads();

    // ---- phase 2: MFMA transform of the 64-node tile ----
    const int w = t >> 6;        // wave 0..7
    const int l = t & 63;
    const int cn = l & 15;       // A-row / B-col selector
    const int ks = l >> 4;       // k-subgroup
    const int s = w & 3;         // node strip (16 nodes)
    const int h = w >> 2;        // fo half (32 cols)
    const int lrow = s * 16 + cn;
    const int arow = n0 + lrow;
    const int aclamp = (arow < NN) ? arow : 0;

    f32x4 acc0 = {0.f, 0.f, 0.f, 0.f};
    f32x4 acc1 = {0.f, 0.f, 0.f, 0.f};

    #pragma unroll
    for (int kb = 0; kb < 4; ++kb) {
        bf16x8 aa;
        if (kb < 2) aa = *(const bf16x8*)(&sA[lrow * 72 + kb * 32 + ks * 8]);
        else        aa = *(const bf16x8*)(feat + (size_t)aclamp * 64 + (kb - 2) * 32 + ks * 8);
        const unsigned short* wb = Wc + cn * 128 + kb * 32 + ks * 8;
        bf16x8 b0 = *(const bf16x8*)(wb + (size_t)(2 * h) * 16 * 128);
        bf16x8 b1 = *(const bf16x8*)(wb + (size_t)(2 * h + 1) * 16 * 128);
        acc0 = __builtin_amdgcn_mfma_f32_16x16x32_bf16(aa, b0, acc0, 0, 0, 0);
        acc1 = __builtin_amdgcn_mfma_f32_16x16x32_bf16(aa, b1, acc1, 0, 0, 0);
    }

    // C/D layout: col = lane&15, row = (lane>>4)*4 + r
    #pragma unroll
    for (int fb = 0; fb < 2; ++fb) {
        f32x4 av = fb ? acc1 : acc0;
        int f = 2 * h + fb;
        float bv = bias[f * 16 + cn];
        #pragma unroll
        for (int r = 0; r < 4; ++r) {
            int node = n0 + s * 16 + ks * 4 + r;
            if (node < NN) {
                float val = av[r] + bv;
                if (Cb) Cb[(size_t)node * 64 + f * 16 + cn] = f2bf(val);
                else    Cf[(size_t)node * 64 + f * 16 + cn] = val;
            }
        }
    }
}

// ---- host ------------------------------------------------------------------

extern "C" void kernel_launch(void* const* d_in, const int* in_sizes, int n_in,
                              void* d_out, int out_size, void* d_ws, size_t ws_size,
                              hipStream_t stream) {
    const float* x   = (const float*)d_in[0];
    const int*   ei  = (const int*)d_in[1];
    const int*   src = ei;
    const int*   dst = ei + NE;
    const float* Wl1 = (const float*)d_in[2];
    const float* b1  = (const float*)d_in[3];
    const float* Wr1 = (const float*)d_in[4];
    const float* Wl2 = (const float*)d_in[5];
    const float* b2  = (const float*)d_in[6];
    const float* Wr2 = (const float*)d_in[7];
    float* out = (float*)d_out;

    char* ws = (char*)d_ws;
    size_t off = 0;
    auto alloc = [&](size_t bytes) {
        void* p = ws + off;
        off = (off + bytes + 255) & ~(size_t)255;
        return p;
    };
    unsigned short* xb     = (unsigned short*)alloc(2 * (size_t)NN * 64);   // 12.8 MB
    unsigned short* h1b    = (unsigned short*)alloc(2 * (size_t)NN * 64);   // 12.8 MB
    unsigned*       binned = (unsigned*)alloc(sizeof(unsigned) * NB * BCAP);// 7.2 MB
    int2*           noff   = (int2*)alloc(sizeof(int2) * NN);
    float*          inv    = (float*)alloc(sizeof(float) * NN);
    int*            gcur   = (int*)alloc(sizeof(int) * NB);
    unsigned short* Wc1    = (unsigned short*)alloc(2 * 64 * 128);
    unsigned short* Wc2    = (unsigned short*)alloc(2 * 64 * 128);

    // prep (gcur + weights + x->bf16), then CSR build — reused by both layers
    k_prep<<<(NN * 64 / 8 + 255) / 256, 256, 0, stream>>>(x, xb, Wl1, Wr1, Wl2, Wr2,
                                                          Wc1, Wc2, gcur);
    k_bin <<<BIN_BLKS, 256, 0, stream>>>(src, dst, gcur, binned);
    k_csr <<<NB, 256, 0, stream>>>(gcur, binned, noff, inv);

    // layer 1: h1b (bf16) = [agg(xb) | xb] @ Wc1^T + b1
    k_fused<<<(NN + 63) / 64, 512, 0, stream>>>(xb, noff, binned, inv, Wc1, b1,
                                                (float*)nullptr, h1b);
    // layer 2: out (f32) = [agg(h1b) | h1b] @ Wc2^T + b2
    k_fused<<<(NN + 63) / 64, 512, 0, stream>>>(h1b, noff, binned, inv, Wc2, b2,
                                                out, (unsigned short*)nullptr);
}